// Round 6
// baseline (140.539 us; speedup 1.0000x reference)
//
#include <hip/hip_runtime.h>
#include <stdint.h>

// graph_smooth: x = node_features @ Emb; A[src,dst] = w (last write wins);
// out = A^3 @ x.  N=4096, E=131072, D_EMB=128, D_OUT=64, K=3.
//
// Dispatch-overhead-bound -> 2 graph nodes:
//   N0 memset(cnt + barrier counters, 16.6 KB)
//   N1 ONE cooperative kernel:
//        P0 scatter-all-edges + embed   (independent -> no barrier between)
//        B1 | P1 dedup + hop1 | B2 | P2 hop2 | B3 | P3 hop3 -> out
// Hand-rolled 2-level tree barrier (NOT cg::grid.sync, which measured
// ~120us/sync in R3): 1 atomicAdd per block into 32 group counters, group
// closers bump root, thread0 spins on root with s_sleep backoff.
// __threadfence() release/acquire around it handles cross-XCD L2
// writeback/invalidate (Guideline 16).

#define N_NODES 4096
#define D_EMB   128
#define D_OUT   64

#define CAPN      128   // bin slots per row; Poisson(32) tail ~1e-40
#define CAP_SHIFT 7

#define NBLK   512
#define NTHR   256
#define NWAVES (NBLK * (NTHR / 64))   // 2048 waves -> 2 rows per wave
#define NGRP   (NBLK / 16)            // 32 barrier groups of 16 blocks

// 2-level grid barrier. All blocks co-resident (cooperative launch, 2
// blocks/CU). grp/root are cumulative; epoch e completes when root == 32*e.
__device__ __forceinline__ void gbar(int* grp, int* root, int epoch) {
    __syncthreads();                          // block's stores issued (vmcnt drained)
    if (threadIdx.x == 0) {
        __threadfence();                      // release: write back this XCD's L2
        int a = atomicAdd(&grp[blockIdx.x >> 4], 1);
        if (((a + 1) & 15) == 0) atomicAdd(root, 1);
        const int target = NGRP * epoch;
        while (__hip_atomic_load(root, __ATOMIC_RELAXED,
                                 __HIP_MEMORY_SCOPE_AGENT) < target)
            __builtin_amdgcn_s_sleep(2);
        __threadfence();                      // acquire: invalidate stale L1/L2
    }
    __syncthreads();
}

__global__ __launch_bounds__(NTHR, 2)
void fused_kernel(const float* __restrict__ nf,
                  const float* __restrict__ emb,
                  const int* __restrict__ ei,
                  const float* __restrict__ ew,
                  int E,
                  float* __restrict__ out,
                  int* __restrict__ cnt,
                  int* __restrict__ grp,     // [NGRP]
                  int* __restrict__ root,    // [1]
                  int4* __restrict__ slots,  // [N_NODES][CAPN] {dst,w,eid,pad}
                  float* __restrict__ x0,
                  float* __restrict__ x1) {
    __shared__ float srow[4][D_EMB];   // embed staging (per-wave slice)
    __shared__ int   sdst[4][CAPN];    // hop staging (per-wave slice)
    __shared__ int   seid[4][CAPN];
    __shared__ float sw[4][CAPN];

    const int tid  = blockIdx.x * NTHR + threadIdx.x;   // 0 .. 131071 == E
    const int wave = threadIdx.x >> 6;
    const int lane = threadIdx.x & 63;
    const int gw   = blockIdx.x * (NTHR / 64) + wave;   // 0 .. 2047

    // ---------------- P0a: scatter every edge into its row bin ----------------
    if (tid < E) {
        int src = ei[tid];
        int dst = ei[E + tid];
        int idx = atomicAdd(&cnt[src], 1);
        if (idx < CAPN) {
            int4 s;
            s.x = dst;
            s.y = __float_as_int(ew[tid]);
            s.z = tid;
            s.w = 0;
            slots[(src << CAP_SHIFT) + idx] = s;
        }
    }

    // ---------------- P0b: embed x0 = nf @ Emb (2 rows per wave) ----------------
    for (int row = gw; row < N_NODES; row += NWAVES) {
        float2 a = ((const float2*)(nf + (size_t)row * D_EMB))[lane];
        srow[wave][2 * lane]     = a.x;
        srow[wave][2 * lane + 1] = a.y;   // wave-private slice; waitcnt suffices
        float acc = 0.0f;
#pragma unroll 8
        for (int k = 0; k < D_EMB; ++k)
            acc = fmaf(srow[wave][k], emb[k * D_OUT + lane], acc);
        x0[row * D_OUT + lane] = acc;
    }

    gbar(grp, root, 1);

    // ---------------- P1: dedup (max eid per dst wins) + hop1 ----------------
    for (int row = gw; row < N_NODES; row += NWAVES) {
        int c = cnt[row];
        if (c > CAPN) c = CAPN;
        int4* s = slots + ((long)row << CAP_SHIFT);
#pragma unroll
        for (int half = 0; half < 2; ++half) {
            int i = lane + half * 64;
            if (i < c) {
                int4 si = s[i];
                sdst[wave][i] = si.x;
                sw[wave][i]   = __int_as_float(si.y);
                seid[wave][i] = si.z;
            }
        }
        // dedup: entry i loses if some j has same dst and larger eid
#pragma unroll
        for (int half = 0; half < 2; ++half) {
            int i = lane + half * 64;
            if (i < c) {
                int d = sdst[wave][i], id = seid[wave][i];
                bool loser = false;
                for (int j = 0; j < c; ++j)
                    loser |= (sdst[wave][j] == d) & (seid[wave][j] > id);
                if (loser) {
                    sw[wave][i] = 0.0f;
                    ((int*)&s[i])[1] = 0;   // hops 2-3 see deduped weight
                }
            }
        }
        float acc = 0.0f;
        int i = 0;
        for (; i + 8 <= c; i += 8) {
            float vw[8], vx[8];
            int vd[8];
#pragma unroll
            for (int k = 0; k < 8; ++k) vw[k] = sw[wave][i + k];
#pragma unroll
            for (int k = 0; k < 8; ++k) vd[k] = sdst[wave][i + k];
#pragma unroll
            for (int k = 0; k < 8; ++k) vx[k] = x0[vd[k] * D_OUT + lane];
#pragma unroll
            for (int k = 0; k < 8; ++k) acc = fmaf(vw[k], vx[k], acc);
        }
        for (; i < c; ++i)
            acc = fmaf(sw[wave][i], x0[sdst[wave][i] * D_OUT + lane], acc);
        x1[row * D_OUT + lane] = acc;
    }

    gbar(grp, root, 2);

    // ---------------- P2: hop2  (x1 -> x0) ----------------
    for (int row = gw; row < N_NODES; row += NWAVES) {
        int c = cnt[row];
        if (c > CAPN) c = CAPN;
        const int4* s = slots + ((long)row << CAP_SHIFT);
#pragma unroll
        for (int half = 0; half < 2; ++half) {
            int i = lane + half * 64;
            if (i < c) {
                int4 si = s[i];
                sdst[wave][i] = si.x;
                sw[wave][i]   = __int_as_float(si.y);
            }
        }
        float acc = 0.0f;
        int i = 0;
        for (; i + 8 <= c; i += 8) {
            float vw[8], vx[8];
            int vd[8];
#pragma unroll
            for (int k = 0; k < 8; ++k) vw[k] = sw[wave][i + k];
#pragma unroll
            for (int k = 0; k < 8; ++k) vd[k] = sdst[wave][i + k];
#pragma unroll
            for (int k = 0; k < 8; ++k) vx[k] = x1[vd[k] * D_OUT + lane];
#pragma unroll
            for (int k = 0; k < 8; ++k) acc = fmaf(vw[k], vx[k], acc);
        }
        for (; i < c; ++i)
            acc = fmaf(sw[wave][i], x1[sdst[wave][i] * D_OUT + lane], acc);
        x0[row * D_OUT + lane] = acc;
    }

    gbar(grp, root, 3);

    // ---------------- P3: hop3  (x0 -> out) ----------------
    for (int row = gw; row < N_NODES; row += NWAVES) {
        int c = cnt[row];
        if (c > CAPN) c = CAPN;
        const int4* s = slots + ((long)row << CAP_SHIFT);
#pragma unroll
        for (int half = 0; half < 2; ++half) {
            int i = lane + half * 64;
            if (i < c) {
                int4 si = s[i];
                sdst[wave][i] = si.x;
                sw[wave][i]   = __int_as_float(si.y);
            }
        }
        float acc = 0.0f;
        int i = 0;
        for (; i + 8 <= c; i += 8) {
            float vw[8], vx[8];
            int vd[8];
#pragma unroll
            for (int k = 0; k < 8; ++k) vw[k] = sw[wave][i + k];
#pragma unroll
            for (int k = 0; k < 8; ++k) vd[k] = sdst[wave][i + k];
#pragma unroll
            for (int k = 0; k < 8; ++k) vx[k] = x0[vd[k] * D_OUT + lane];
#pragma unroll
            for (int k = 0; k < 8; ++k) acc = fmaf(vw[k], vx[k], acc);
        }
        for (; i < c; ++i)
            acc = fmaf(sw[wave][i], x0[sdst[wave][i] * D_OUT + lane], acc);
        out[row * D_OUT + lane] = acc;
    }
}

extern "C" void kernel_launch(void* const* d_in, const int* in_sizes, int n_in,
                              void* d_out, int out_size, void* d_ws, size_t ws_size,
                              hipStream_t stream) {
    const float* nf  = (const float*)d_in[0];   // [N, 128]
    const float* emb = (const float*)d_in[1];   // [128, 64]
    const int*   ei  = (const int*)d_in[2];     // [2, E]
    const float* ew  = (const float*)d_in[3];   // [E]
    float* out = (float*)d_out;                 // [N, 64]

    int E = in_sizes[3];

    // ---- workspace carve-out; cnt|grp|root are CONTIGUOUS -> one memset ----
    char* ws = (char*)d_ws;
    size_t o = 0;
    auto take = [&](size_t bytes) -> void* {
        void* p = ws + o;
        o += (bytes + 255) & ~(size_t)255;
        return p;
    };
    int*  cnt  = (int*)take((size_t)N_NODES * 4);          // 16384 B
    int*  grp  = (int*)take((size_t)NGRP * 4 + 4);         // grp[32] + root
    int*  root = grp + NGRP;
    size_t zero_bytes = o;                                  // covers cnt+grp+root
    int4* slots = (int4*)take((size_t)N_NODES * CAPN * 16);
    float* x0   = (float*)take((size_t)N_NODES * D_OUT * 4);
    float* x1   = (float*)take((size_t)N_NODES * D_OUT * 4);

    hipMemsetAsync(cnt, 0, zero_bytes, stream);             // N0

    void* args[] = {(void*)&nf, (void*)&emb, (void*)&ei, (void*)&ew, (void*)&E,
                    (void*)&out, (void*)&cnt, (void*)&grp, (void*)&root,
                    (void*)&slots, (void*)&x0, (void*)&x1};
    hipLaunchCooperativeKernel((const void*)fused_kernel, dim3(NBLK), dim3(NTHR),
                               args, 0, stream);            // N1
}

// Round 7
// 50.702 us; speedup vs baseline: 2.7719x; 2.7719x over previous
//
#include <hip/hip_runtime.h>
#include <stdint.h>

// graph_smooth: x = node_features @ Emb; A[src,dst] = w (last write wins);
// out = A^3 @ x.  N=4096, E=131072, D_EMB=128, D_OUT=64, K=3.
//
// Launch-bound: 5 graph nodes is the sync floor (zero -> scatter -> hop1 ->
// hop2 -> hop3). In-kernel grid barriers measured 35-120us/sync on this chip
// (R3/R6) vs ~4us per kernel boundary -> multi-dispatch wins.
//   N0 memset(cnt, 16KB) | N1 fused embed+scatter | N2 dedup+hop1 |
//   N3 hop2 | N4 hop3.
// Bins: int4 {dst, w_bits, eid, pad}. Dedup (numpy last-write-wins = max eid
// per (src,dst)) runs in hop1's wave; losers get w=0 written back so hops
// 2-3 see deduped bins. Hops 2-3 read bins as uniform int2 broadcasts
// (no LDS staging -- wave-uniform address is already a 1-transaction load).

#define N_NODES 4096
#define D_EMB   128
#define D_OUT   64

#define CAPN      128   // slots per row incl. duplicates; Poisson(32) tail ~1e-40
#define CAP_SHIFT 7

// ---- N1: blocks 0..1023 embed (4 waves x 1 row), blocks 1024..1535 scatter.
__global__ void embed_scatter_kernel(const float* __restrict__ nf,
                                     const float* __restrict__ emb,
                                     float* __restrict__ x,
                                     const int* __restrict__ ei,
                                     const float* __restrict__ ew, int E,
                                     int* __restrict__ cnt,
                                     int4* __restrict__ slots) {
    if (blockIdx.x < 1024) {
        // ---- embed: x[row,:] = nf[row,:] @ emb ----
        __shared__ float srow[4][D_EMB];
        int wave = threadIdx.x >> 6;
        int lane = threadIdx.x & 63;
        int row  = blockIdx.x * 4 + wave;
        float2 a = ((const float2*)(nf + (size_t)row * D_EMB))[lane];
        srow[wave][2 * lane]     = a.x;
        srow[wave][2 * lane + 1] = a.y;
        __syncthreads();
        float acc = 0.0f;
#pragma unroll 8
        for (int k = 0; k < D_EMB; ++k)
            acc = fmaf(srow[wave][k], emb[k * D_OUT + lane], acc);
        x[row * D_OUT + lane] = acc;
    } else {
        // ---- scatter: bin every edge (incl. duplicates) by src ----
        int e = (blockIdx.x - 1024) * blockDim.x + threadIdx.x;
        if (e >= E) return;
        int src = ei[e];
        int dst = ei[E + e];
        int idx = atomicAdd(&cnt[src], 1);
        if (idx < CAPN) {
            int4 s;
            s.x = dst;
            s.y = __float_as_int(ew[e]);
            s.z = e;
            s.w = 0;
            slots[(src << CAP_SHIFT) + idx] = s;
        }
    }
}

// ---- N2: per-row dedup (keep max eid per dst) + hop1; one wave per row ----
__global__ void dedup_spmm_kernel(const int* __restrict__ cnt,
                                  int4* __restrict__ slots,
                                  const float* __restrict__ x,
                                  float* __restrict__ y) {
    __shared__ int   sdst[4][CAPN];
    __shared__ int   seid[4][CAPN];
    __shared__ float sw[4][CAPN];

    int wave = threadIdx.x >> 6;
    int lane = threadIdx.x & 63;
    int row  = blockIdx.x * 4 + wave;
    int c = cnt[row];
    if (c > CAPN) c = CAPN;
    int4* s = slots + ((long)row << CAP_SHIFT);

#pragma unroll
    for (int half = 0; half < 2; ++half) {
        int i = lane + half * 64;
        if (i < c) {
            int4 si = s[i];
            sdst[wave][i] = si.x;
            sw[wave][i]   = __int_as_float(si.y);
            seid[wave][i] = si.z;
        }
    }
    __syncthreads();

    // dedup: entry i loses if some j has same dst and larger eid
#pragma unroll
    for (int half = 0; half < 2; ++half) {
        int i = lane + half * 64;
        if (i < c) {
            int d = sdst[wave][i], id = seid[wave][i];
            bool loser = false;
            for (int j = 0; j < c; ++j)
                loser |= (sdst[wave][j] == d) & (seid[wave][j] > id);
            if (loser) {
                sw[wave][i] = 0.0f;
                ((int*)&s[i])[1] = 0;   // hops 2-3 see deduped weight
            }
        }
    }
    __syncthreads();

    // hop 1, 8-deep gather ILP
    float acc = 0.0f;
    int i = 0;
    for (; i + 8 <= c; i += 8) {
        float vw[8], vx[8];
        int vd[8];
#pragma unroll
        for (int k = 0; k < 8; ++k) vw[k] = sw[wave][i + k];
#pragma unroll
        for (int k = 0; k < 8; ++k) vd[k] = sdst[wave][i + k];
#pragma unroll
        for (int k = 0; k < 8; ++k) vx[k] = x[vd[k] * D_OUT + lane];
#pragma unroll
        for (int k = 0; k < 8; ++k) acc = fmaf(vw[k], vx[k], acc);
    }
    for (; i < c; ++i)
        acc = fmaf(sw[wave][i], x[sdst[wave][i] * D_OUT + lane], acc);
    y[row * D_OUT + lane] = acc;
}

// ---- N3/N4: plain SpMM hop; bins read as wave-uniform int2 broadcasts ----
__global__ void spmm_kernel(const int* __restrict__ cnt,
                            const int4* __restrict__ slots,
                            const float* __restrict__ x,
                            float* __restrict__ y) {
    int wave = threadIdx.x >> 6;
    int lane = threadIdx.x & 63;
    int row  = blockIdx.x * 4 + wave;
    int c = cnt[row];
    if (c > CAPN) c = CAPN;
    // {dst, w_bits} is the first 8B of each 16B slot
    const int2* s = (const int2*)(slots + ((long)row << CAP_SHIFT));

    float acc = 0.0f;
    int i = 0;
    for (; i + 8 <= c; i += 8) {
        int2 e[8];
#pragma unroll
        for (int k = 0; k < 8; ++k) e[k] = s[2 * (i + k)];
        float vx[8];
#pragma unroll
        for (int k = 0; k < 8; ++k) vx[k] = x[e[k].x * D_OUT + lane];
#pragma unroll
        for (int k = 0; k < 8; ++k)
            acc = fmaf(__int_as_float(e[k].y), vx[k], acc);
    }
    for (; i < c; ++i) {
        int2 ee = s[2 * i];
        acc = fmaf(__int_as_float(ee.y), x[ee.x * D_OUT + lane], acc);
    }
    y[row * D_OUT + lane] = acc;
}

extern "C" void kernel_launch(void* const* d_in, const int* in_sizes, int n_in,
                              void* d_out, int out_size, void* d_ws, size_t ws_size,
                              hipStream_t stream) {
    const float* nf  = (const float*)d_in[0];   // [N, 128]
    const float* emb = (const float*)d_in[1];   // [128, 64]
    const int*   ei  = (const int*)d_in[2];     // [2, E]
    const float* ew  = (const float*)d_in[3];   // [E]
    float* out = (float*)d_out;                 // [N, 64]

    const int E = in_sizes[3];

    // ---- workspace carve-out (256B-aligned) ----
    char* ws = (char*)d_ws;
    size_t o = 0;
    auto take = [&](size_t bytes) -> void* {
        void* p = ws + o;
        o += (bytes + 255) & ~(size_t)255;
        return p;
    };
    int*  cnt   = (int*)take((size_t)N_NODES * 4);
    int4* slots = (int4*)take((size_t)N_NODES * CAPN * 16);
    float* x0   = (float*)take((size_t)N_NODES * D_OUT * 4);
    float* x1   = (float*)take((size_t)N_NODES * D_OUT * 4);

    const int TB = 256;
    const int NB = N_NODES / 4;                       // 1024
    const int SB = (E + TB - 1) / TB;                 // 512

    hipMemsetAsync(cnt, 0, (size_t)N_NODES * 4, stream);            // N0
    embed_scatter_kernel<<<NB + SB, TB, 0, stream>>>(nf, emb, x0,   // N1
                                                     ei, ew, E, cnt, slots);
    dedup_spmm_kernel<<<NB, TB, 0, stream>>>(cnt, slots, x0, x1);   // N2
    spmm_kernel<<<NB, TB, 0, stream>>>(cnt, slots, x1, x0);         // N3
    spmm_kernel<<<NB, TB, 0, stream>>>(cnt, slots, x0, out);        // N4
}

// Round 8
// 46.530 us; speedup vs baseline: 3.0204x; 1.0897x over previous
//
#include <hip/hip_runtime.h>
#include <stdint.h>

// graph_smooth: x = node_features @ Emb; A[src,dst] = w (last write wins);
// out = A^3 @ x.  N=4096, E=131072, D_EMB=128, D_OUT=64, K=3.
//
// Launch-bound: 5 graph nodes is the sync floor (zero -> scatter -> hop1 ->
// hop2 -> hop3). In-kernel grid barriers measured 35-120us/sync (R3/R6) vs
// ~4us per kernel boundary -> multi-dispatch wins. LDS-staged bins in the
// hop kernels measured +6us when removed (R7) -> keep (breaks the L2->L2
// dependent-load chain).
//   N0 memset(cnt,16KB) | N1 fused scatter+embed | N2 dedup+hop1 |
//   N3 hop2 | N4 hop3.
// Bins split: pairs{dst,w_bits} 8B (all hops) + eids 4B (dedup only).
// Dedup (numpy last-write-wins = max eid per (src,dst)) runs in hop1's wave;
// losers get w=0 written back so hops 2-3 see deduped bins.

#define N_NODES 4096
#define D_EMB   128
#define D_OUT   64

#define CAPN      128   // slots per row incl. duplicates; Poisson(32) tail ~1e-40
#define CAP_SHIFT 7

// ---- N1: blocks 0..511 scatter, blocks 512..1535 embed (4 waves x 1 row) ----
__global__ void scatter_embed_kernel(const float* __restrict__ nf,
                                     const float* __restrict__ emb,
                                     float* __restrict__ x,
                                     const int* __restrict__ ei,
                                     const float* __restrict__ ew, int E,
                                     int* __restrict__ cnt,
                                     int2* __restrict__ pairs,
                                     int* __restrict__ eids) {
    if (blockIdx.x < 512) {
        // ---- scatter: bin every edge (incl. duplicates) by src ----
        int e = blockIdx.x * blockDim.x + threadIdx.x;
        if (e >= E) return;
        int src = ei[e];
        int dst = ei[E + e];
        int idx = atomicAdd(&cnt[src], 1);
        if (idx < CAPN) {
            int p = (src << CAP_SHIFT) + idx;
            int2 pr;
            pr.x = dst;
            pr.y = __float_as_int(ew[e]);
            pairs[p] = pr;
            eids[p]  = e;
        }
    } else {
        // ---- embed: x[row,:] = nf[row,:] @ emb ----
        __shared__ float srow[4][D_EMB];
        int wave = threadIdx.x >> 6;
        int lane = threadIdx.x & 63;
        int row  = (blockIdx.x - 512) * 4 + wave;
        float2 a = ((const float2*)(nf + (size_t)row * D_EMB))[lane];
        srow[wave][2 * lane]     = a.x;
        srow[wave][2 * lane + 1] = a.y;
        __syncthreads();
        float acc = 0.0f;
#pragma unroll 8
        for (int k = 0; k < D_EMB; ++k)
            acc = fmaf(srow[wave][k], emb[k * D_OUT + lane], acc);
        x[row * D_OUT + lane] = acc;
    }
}

// ---- N2: per-row dedup (keep max eid per dst) + hop1; one wave per row ----
__global__ void dedup_spmm_kernel(const int* __restrict__ cnt,
                                  int2* __restrict__ pairs,
                                  const int* __restrict__ eids,
                                  const float* __restrict__ x,
                                  float* __restrict__ y) {
    __shared__ int   sdst[4][CAPN];
    __shared__ int   seid[4][CAPN];
    __shared__ float sw[4][CAPN];

    int wave = threadIdx.x >> 6;
    int lane = threadIdx.x & 63;
    int row  = blockIdx.x * 4 + wave;
    int c = cnt[row];
    if (c > CAPN) c = CAPN;
    int2* sp = pairs + ((long)row << CAP_SHIFT);
    const int* se = eids + ((long)row << CAP_SHIFT);

#pragma unroll
    for (int half = 0; half < 2; ++half) {
        int i = lane + half * 64;
        if (i < c) {
            int2 pr = sp[i];
            sdst[wave][i] = pr.x;
            sw[wave][i]   = __int_as_float(pr.y);
            seid[wave][i] = se[i];
        }
    }
    __syncthreads();

    // dedup: entry i loses if some j has same dst and larger eid
#pragma unroll
    for (int half = 0; half < 2; ++half) {
        int i = lane + half * 64;
        if (i < c) {
            int d = sdst[wave][i], id = seid[wave][i];
            bool loser = false;
            for (int j = 0; j < c; ++j)
                loser |= (sdst[wave][j] == d) & (seid[wave][j] > id);
            if (loser) {
                sw[wave][i] = 0.0f;
                sp[i].y = 0;   // hops 2-3 see deduped weight
            }
        }
    }
    __syncthreads();

    // hop 1, 8-deep gather ILP
    float acc = 0.0f;
    int i = 0;
    for (; i + 8 <= c; i += 8) {
        float vw[8], vx[8];
        int vd[8];
#pragma unroll
        for (int k = 0; k < 8; ++k) vw[k] = sw[wave][i + k];
#pragma unroll
        for (int k = 0; k < 8; ++k) vd[k] = sdst[wave][i + k];
#pragma unroll
        for (int k = 0; k < 8; ++k) vx[k] = x[vd[k] * D_OUT + lane];
#pragma unroll
        for (int k = 0; k < 8; ++k) acc = fmaf(vw[k], vx[k], acc);
    }
    for (; i < c; ++i)
        acc = fmaf(sw[wave][i], x[sdst[wave][i] * D_OUT + lane], acc);
    y[row * D_OUT + lane] = acc;
}

// ---- N3/N4: plain SpMM hop with LDS-staged 8B bins; one wave per row ----
__global__ void spmm_kernel(const int* __restrict__ cnt,
                            const int2* __restrict__ pairs,
                            const float* __restrict__ x,
                            float* __restrict__ y) {
    __shared__ int   sdst[4][CAPN];
    __shared__ float sw[4][CAPN];

    int wave = threadIdx.x >> 6;
    int lane = threadIdx.x & 63;
    int row  = blockIdx.x * 4 + wave;
    int c = cnt[row];
    if (c > CAPN) c = CAPN;
    const int2* sp = pairs + ((long)row << CAP_SHIFT);

#pragma unroll
    for (int half = 0; half < 2; ++half) {
        int i = lane + half * 64;
        if (i < c) {
            int2 pr = sp[i];
            sdst[wave][i] = pr.x;
            sw[wave][i]   = __int_as_float(pr.y);
        }
    }
    __syncthreads();

    float acc = 0.0f;
    int i = 0;
    for (; i + 8 <= c; i += 8) {
        float vw[8], vx[8];
        int vd[8];
#pragma unroll
        for (int k = 0; k < 8; ++k) vw[k] = sw[wave][i + k];
#pragma unroll
        for (int k = 0; k < 8; ++k) vd[k] = sdst[wave][i + k];
#pragma unroll
        for (int k = 0; k < 8; ++k) vx[k] = x[vd[k] * D_OUT + lane];
#pragma unroll
        for (int k = 0; k < 8; ++k) acc = fmaf(vw[k], vx[k], acc);
    }
    for (; i < c; ++i)
        acc = fmaf(sw[wave][i], x[sdst[wave][i] * D_OUT + lane], acc);
    y[row * D_OUT + lane] = acc;
}

extern "C" void kernel_launch(void* const* d_in, const int* in_sizes, int n_in,
                              void* d_out, int out_size, void* d_ws, size_t ws_size,
                              hipStream_t stream) {
    const float* nf  = (const float*)d_in[0];   // [N, 128]
    const float* emb = (const float*)d_in[1];   // [128, 64]
    const int*   ei  = (const int*)d_in[2];     // [2, E]
    const float* ew  = (const float*)d_in[3];   // [E]
    float* out = (float*)d_out;                 // [N, 64]

    const int E = in_sizes[3];

    // ---- workspace carve-out (256B-aligned) ----
    char* ws = (char*)d_ws;
    size_t o = 0;
    auto take = [&](size_t bytes) -> void* {
        void* p = ws + o;
        o += (bytes + 255) & ~(size_t)255;
        return p;
    };
    int*  cnt   = (int*)take((size_t)N_NODES * 4);
    int2* pairs = (int2*)take((size_t)N_NODES * CAPN * 8);
    int*  eids  = (int*)take((size_t)N_NODES * CAPN * 4);
    float* x0   = (float*)take((size_t)N_NODES * D_OUT * 4);
    float* x1   = (float*)take((size_t)N_NODES * D_OUT * 4);

    const int TB = 256;
    const int NB = N_NODES / 4;                       // 1024
    const int SB = (E + TB - 1) / TB;                 // 512

    hipMemsetAsync(cnt, 0, (size_t)N_NODES * 4, stream);            // N0
    scatter_embed_kernel<<<SB + NB, TB, 0, stream>>>(nf, emb, x0,   // N1
                                                     ei, ew, E, cnt,
                                                     pairs, eids);
    dedup_spmm_kernel<<<NB, TB, 0, stream>>>(cnt, pairs, eids, x0, x1);  // N2
    spmm_kernel<<<NB, TB, 0, stream>>>(cnt, pairs, x1, x0);              // N3
    spmm_kernel<<<NB, TB, 0, stream>>>(cnt, pairs, x0, out);             // N4
}